// Round 5
// baseline (110.249 us; speedup 1.0000x reference)
//
#include <hip/hip_runtime.h>

#define BATCH 8
#define NPTS 16384
#define MSKEL 1000
#define NCLS 100
#define CKK 10
#define MINDIS_INITF 100000.0f

// ws float layout (16B aligned):
//   skelN   : [0, 32000)        float4 (-sx,-sy,-sz, 0.5|s|^2) per (b,m)
//   ptsM    : [32000, 556288)   float4 (x,y,z, 0.5|p|^2)       per (b,n)
//   tileMins: [556288, 1068288) d^2 at [ (b*64+tile)*1000 + m ]  (64 tiles)
//   partials: [1068288, 1068800) n-side per-block sums (512)
#define OFF_PTSM 32000
#define OFF_TMIN (32000 + 524288)
#define OFF_PART (32000 + 524288 + 512000)

// prep: build skelN and ptsM; zero the output accumulator.
__global__ __launch_bounds__(256) void k_prep(const float* __restrict__ xyz,
                                              const float* __restrict__ skel,
                                              float4* __restrict__ skelN,
                                              float4* __restrict__ ptsM,
                                              float* __restrict__ out) {
    const int gid = blockIdx.x * 256 + threadIdx.x;  // 131072 threads exactly
    {
        const float* p = xyz + (size_t)gid * 6;
        float x = p[0], y = p[1], z = p[2];
        ptsM[gid] = make_float4(x, y, z, 0.5f * (x * x + y * y + z * z));
    }
    if (gid < BATCH * MSKEL) {
        const float* s = skel + (size_t)gid * 3;
        float sx = s[0], sy = s[1], sz = s[2];
        skelN[gid] = make_float4(-sx, -sy, -sz, 0.5f * (sx * sx + sy * sy + sz * sz));
    }
    if (gid == 0) out[0] = 0.0f;
}

// Fused chamfer, 1024 blocks (4/CU, 16 waves/CU). Hot loops: per-pair
// t = half_sq - dot via 3 FMA + 1 min; wave-uniform operand streams on the
// scalar pipe (uniform index -> s_load_dwordx4).
//   blocks [0,512):    n-side — 256-pt tile, 1 pt/thread, 2-way m-unroll
//                      with independent min accumulators. d^2 = 2(mt + 0.5|p|^2).
//   blocks [512,1024): m-side — 4 skel/thread in regs, 256-pt tile uniform.
//                      d^2 = 2*min_t + |s|^2.
__global__ __launch_bounds__(256) void k_chamfer(const float4* __restrict__ skelN,
                                                 const float4* __restrict__ ptsM,
                                                 float* __restrict__ tileMins,
                                                 float* __restrict__ partials) {
    const int bid = blockIdx.x;
    const int tid = threadIdx.x;

    if (bid < 512) {
        // ---------------- n-side ----------------
        const int b = bid >> 6, tile = bid & 63;
        const float4 r = ptsM[b * NPTS + tile * 256 + tid];
        const float4* __restrict__ sk = skelN + b * MSKEL;

        float mtA = 3.4e38f, mtB = 3.4e38f;
#pragma unroll 4
        for (int m = 0; m < MSKEL; m += 2) {
            float4 sa = sk[m];      // uniform -> scalar pipe
            float4 sb = sk[m + 1];
            float ta = fmaf(r.x, sa.x, fmaf(r.y, sa.y, fmaf(r.z, sa.z, sa.w)));
            float tb = fmaf(r.x, sb.x, fmaf(r.y, sb.y, fmaf(r.z, sb.z, sb.w)));
            mtA = fminf(mtA, ta);
            mtB = fminf(mtB, tb);
        }
        float mt = fminf(mtA, mtB);
        float d = sqrtf(fmaxf(2.0f * (mt + r.w), 1e-12f));

#pragma unroll
        for (int o = 32; o > 0; o >>= 1) d += __shfl_down(d, o, 64);
        __shared__ float s_part[4];
        const int wave = tid >> 6, lane = tid & 63;
        if (lane == 0) s_part[wave] = d;
        __syncthreads();
        if (tid == 0) partials[bid] = s_part[0] + s_part[1] + s_part[2] + s_part[3];
    } else {
        // ---------------- m-side ----------------
        const int id = bid - 512;
        const int b = id >> 6, tile = id & 63;

        float nsx[4], nsy[4], nsz[4], ssq[4], mind[4];
#pragma unroll
        for (int k = 0; k < 4; ++k) {
            const int m = tid + k * 256;
            if (m < MSKEL) {
                float4 s = skelN[b * MSKEL + m];  // coalesced
                nsx[k] = s.x; nsy[k] = s.y; nsz[k] = s.z;  // already -s
                ssq[k] = 2.0f * s.w;                        // |s|^2
            } else {
                nsx[k] = 0.0f; nsy[k] = 0.0f; nsz[k] = 0.0f; ssq[k] = 0.0f;
            }
            mind[k] = 3.4e38f;
        }

        const float4* __restrict__ pp = ptsM + b * NPTS + tile * 256;
#pragma unroll 8
        for (int n = 0; n < 256; ++n) {
            float4 r = pp[n];  // uniform -> scalar pipe
#pragma unroll
            for (int k = 0; k < 4; ++k) {
                float t = fmaf(r.x, nsx[k], fmaf(r.y, nsy[k], fmaf(r.z, nsz[k], r.w)));
                mind[k] = fminf(mind[k], t);
            }
        }
        float* tm = tileMins + (size_t)(b * 64 + tile) * MSKEL;
#pragma unroll
        for (int k = 0; k < 4; ++k) {
            const int m = tid + k * 256;
            if (m < MSKEL) tm[m] = fmaf(2.0f, mind[k], ssq[k]);  // d^2, coalesced
        }
    }
}

// reduce: m-side 64-way min (coalesced) + n-side partials + convex-hull term;
// one atomicAdd per block into out[0] (pre-scaled).
__global__ __launch_bounds__(256) void k_reduce(const float* __restrict__ skel,
                                                const int* __restrict__ labels,
                                                const float* __restrict__ tileMins,
                                                const float* __restrict__ partials,
                                                float* __restrict__ out) {
    const int gid = blockIdx.x * 256 + threadIdx.x;  // 64 blocks = 16384 threads
    const int tid = threadIdx.x;
    float acc = 0.0f;

    if (gid < BATCH * MSKEL) {
        const int b = gid / MSKEL, m = gid - b * MSKEL;
        float mn = 3.4e38f;
#pragma unroll 8
        for (int t = 0; t < 64; ++t) {
            mn = fminf(mn, tileMins[(size_t)(b * 64 + t) * MSKEL + m]);  // coalesced
        }
        acc += 0.0125f * sqrtf(fmaxf(mn, 1e-12f));  // 0.1 / BATCH
    }
    if (gid < 512) acc += 0.0125f * partials[gid];

    if (gid < BATCH * NCLS) {
        const int b = gid / NCLS, c = gid - b * NCLS;
        const float* cp = skel + ((size_t)b * MSKEL + c * CKK) * 3;
        const int* lab = labels + (size_t)b * NCLS * CKK + c * CKK;
        float x[CKK], y[CKK], z[CKK];
        int lv[CKK];
#pragma unroll
        for (int i = 0; i < CKK; ++i) {
            x[i] = cp[i * 3 + 0]; y[i] = cp[i * 3 + 1]; z[i] = cp[i * 3 + 2];
            lv[i] = lab[i];
        }
        float convexSum = 0.0f;
#pragma unroll
        for (int i = 0; i < CKK; ++i) {
            if (lv[i] != 1) {
                float mind = MINDIS_INITF;
#pragma unroll
                for (int j = 0; j < CKK; ++j) {
                    if (lv[j] == 1) {
                        float dx = x[i] - x[j], dy = y[i] - y[j], dz = z[i] - z[j];
                        mind = fminf(mind, dx * dx + dy * dy + dz * dz);
                    }
                }
                convexSum += mind;
            }
        }
        acc += convexSum * (1.0f / (BATCH * NCLS));
    }

#pragma unroll
    for (int o = 32; o > 0; o >>= 1) acc += __shfl_down(acc, o, 64);
    __shared__ float s_part[4];
    const int wave = tid >> 6, lane = tid & 63;
    if (lane == 0) s_part[wave] = acc;
    __syncthreads();
    if (tid == 0) {
        atomicAdd(out, s_part[0] + s_part[1] + s_part[2] + s_part[3]);
    }
}

extern "C" void kernel_launch(void* const* d_in, const int* in_sizes, int n_in,
                              void* d_out, int out_size, void* d_ws, size_t ws_size,
                              hipStream_t stream) {
    const float* xyz = (const float*)d_in[0];
    const float* skel = (const float*)d_in[1];
    // d_in[2] = weights (unused by reference)
    const int* labels = (const int*)d_in[3];
    float* out = (float*)d_out;

    float4* skelN = (float4*)d_ws;
    float4* ptsM = (float4*)((float*)d_ws + OFF_PTSM);
    float* tileMins = (float*)d_ws + OFF_TMIN;
    float* partials = (float*)d_ws + OFF_PART;

    k_prep<<<512, 256, 0, stream>>>(xyz, skel, skelN, ptsM, out);
    k_chamfer<<<1024, 256, 0, stream>>>(skelN, ptsM, tileMins, partials);
    k_reduce<<<64, 256, 0, stream>>>(skel, labels, tileMins, partials, out);
}

// Round 6
// 104.839 us; speedup vs baseline: 1.0516x; 1.0516x over previous
//
#include <hip/hip_runtime.h>

#define BATCH 8
#define NPTS 16384
#define MSKEL 1000
#define NCLS 100
#define CKK 10
#define MINDIS_INITF 100000.0f

// ws float layout (16B aligned):
//   skelN   : [0, 32000)         float4 (-sx,-sy,-sz, 0.5|s|^2) per (b,m)
//   ptsM    : [32000, 556288)    float4 (x,y,z, 0.5|p|^2)       per (b,n)
//   tileMins: [556288, 812288)   d^2 at [ (b*32+tile)*1000 + m ] (32 tiles)
//   partials: [812288, 812544)   n-side per-block sums (256)
#define OFF_PTSM 32000
#define OFF_TMIN (32000 + 524288)
#define OFF_PART (32000 + 524288 + 256000)

// prep: build skelN and ptsM; zero the output accumulator.
__global__ __launch_bounds__(256) void k_prep(const float* __restrict__ xyz,
                                              const float* __restrict__ skel,
                                              float4* __restrict__ skelN,
                                              float4* __restrict__ ptsM,
                                              float* __restrict__ out) {
    const int gid = blockIdx.x * 256 + threadIdx.x;  // 131072 threads exactly
    {
        const float* p = xyz + (size_t)gid * 6;
        float x = p[0], y = p[1], z = p[2];
        ptsM[gid] = make_float4(x, y, z, 0.5f * (x * x + y * y + z * z));
    }
    if (gid < BATCH * MSKEL) {
        const float* s = skel + (size_t)gid * 3;
        float sx = s[0], sy = s[1], sz = s[2];
        skelN[gid] = make_float4(-sx, -sy, -sz, 0.5f * (sx * sx + sy * sy + sz * sz));
    }
    if (gid == 0) out[0] = 0.0f;
}

// Fused chamfer, 512 blocks (2/CU, R4 grid). Per-pair = 3 FMA + 1 min on both
// sides (half-square trick). Wave-uniform operand streams on the scalar pipe.
//   blocks [0,256):   n-side — 512-pt tile, 2 pts/thread, 2 independent
//                     m-chains per point (4 chains total), unroll 8.
//   blocks [256,512): m-side — 4 skel/thread in regs, 512-pt tile uniform.
__global__ __launch_bounds__(256) void k_chamfer(const float4* __restrict__ skelN,
                                                 const float4* __restrict__ ptsM,
                                                 float* __restrict__ tileMins,
                                                 float* __restrict__ partials) {
    const int bid = blockIdx.x;
    const int tid = threadIdx.x;

    if (bid < 256) {
        // ---------------- n-side ----------------
        const int b = bid >> 5, tile = bid & 31;
        const float4 r0 = ptsM[b * NPTS + tile * 512 + tid];
        const float4 r1 = ptsM[b * NPTS + tile * 512 + 256 + tid];
        const float4* __restrict__ sk = skelN + b * MSKEL;

        float m0A = 3.4e38f, m0B = 3.4e38f, m1A = 3.4e38f, m1B = 3.4e38f;
#pragma unroll 4
        for (int m = 0; m < MSKEL; m += 2) {
            float4 sa = sk[m];      // uniform -> s_load_dwordx4
            float4 sb = sk[m + 1];
            float t0a = fmaf(r0.x, sa.x, fmaf(r0.y, sa.y, fmaf(r0.z, sa.z, sa.w)));
            float t1a = fmaf(r1.x, sa.x, fmaf(r1.y, sa.y, fmaf(r1.z, sa.z, sa.w)));
            float t0b = fmaf(r0.x, sb.x, fmaf(r0.y, sb.y, fmaf(r0.z, sb.z, sb.w)));
            float t1b = fmaf(r1.x, sb.x, fmaf(r1.y, sb.y, fmaf(r1.z, sb.z, sb.w)));
            m0A = fminf(m0A, t0a);
            m1A = fminf(m1A, t1a);
            m0B = fminf(m0B, t0b);
            m1B = fminf(m1B, t1b);
        }
        float mt0 = fminf(m0A, m0B), mt1 = fminf(m1A, m1B);
        float d = sqrtf(fmaxf(2.0f * (mt0 + r0.w), 1e-12f)) +
                  sqrtf(fmaxf(2.0f * (mt1 + r1.w), 1e-12f));

#pragma unroll
        for (int o = 32; o > 0; o >>= 1) d += __shfl_down(d, o, 64);
        __shared__ float s_part[4];
        const int wave = tid >> 6, lane = tid & 63;
        if (lane == 0) s_part[wave] = d;
        __syncthreads();
        if (tid == 0) partials[bid] = s_part[0] + s_part[1] + s_part[2] + s_part[3];
    } else {
        // ---------------- m-side ----------------
        const int id = bid - 256;
        const int b = id >> 5, tile = id & 31;

        float nsx[4], nsy[4], nsz[4], ssq[4], mind[4];
#pragma unroll
        for (int k = 0; k < 4; ++k) {
            const int m = tid + k * 256;
            if (m < MSKEL) {
                float4 s = skelN[b * MSKEL + m];  // coalesced
                nsx[k] = s.x; nsy[k] = s.y; nsz[k] = s.z;  // already -s
                ssq[k] = 2.0f * s.w;                        // |s|^2
            } else {
                nsx[k] = 0.0f; nsy[k] = 0.0f; nsz[k] = 0.0f; ssq[k] = 0.0f;
            }
            mind[k] = 3.4e38f;
        }

        const float4* __restrict__ pp = ptsM + b * NPTS + tile * 512;
#pragma unroll 8
        for (int n = 0; n < 512; ++n) {
            float4 r = pp[n];  // uniform -> s_load_dwordx4
#pragma unroll
            for (int k = 0; k < 4; ++k) {
                // t = 0.5|p|^2 - p.s ; d^2 = 2t + |s|^2
                float t = fmaf(r.x, nsx[k], fmaf(r.y, nsy[k], fmaf(r.z, nsz[k], r.w)));
                mind[k] = fminf(mind[k], t);
            }
        }
        float* tm = tileMins + (size_t)(b * 32 + tile) * MSKEL;
#pragma unroll
        for (int k = 0; k < 4; ++k) {
            const int m = tid + k * 256;
            if (m < MSKEL) tm[m] = fmaf(2.0f, mind[k], ssq[k]);  // d^2, coalesced
        }
    }
}

// reduce: m-side 32-way min (coalesced) + n-side partials + convex-hull term;
// one atomicAdd per block into out[0] (pre-scaled).
__global__ __launch_bounds__(256) void k_reduce(const float* __restrict__ skel,
                                                const int* __restrict__ labels,
                                                const float* __restrict__ tileMins,
                                                const float* __restrict__ partials,
                                                float* __restrict__ out) {
    const int gid = blockIdx.x * 256 + threadIdx.x;  // 64 blocks = 16384 threads
    const int tid = threadIdx.x;
    float acc = 0.0f;

    if (gid < BATCH * MSKEL) {
        const int b = gid / MSKEL, m = gid - b * MSKEL;
        float mn = 3.4e38f;
#pragma unroll 8
        for (int t = 0; t < 32; ++t) {
            mn = fminf(mn, tileMins[(size_t)(b * 32 + t) * MSKEL + m]);  // coalesced
        }
        acc += 0.0125f * sqrtf(fmaxf(mn, 1e-12f));  // 0.1 / BATCH
    }
    if (gid < 256) acc += 0.0125f * partials[gid];

    if (gid < BATCH * NCLS) {
        const int b = gid / NCLS, c = gid - b * NCLS;
        const float* cp = skel + ((size_t)b * MSKEL + c * CKK) * 3;
        const int* lab = labels + (size_t)b * NCLS * CKK + c * CKK;
        float x[CKK], y[CKK], z[CKK];
        int lv[CKK];
#pragma unroll
        for (int i = 0; i < CKK; ++i) {
            x[i] = cp[i * 3 + 0]; y[i] = cp[i * 3 + 1]; z[i] = cp[i * 3 + 2];
            lv[i] = lab[i];
        }
        float convexSum = 0.0f;
#pragma unroll
        for (int i = 0; i < CKK; ++i) {
            if (lv[i] != 1) {
                float mind = MINDIS_INITF;
#pragma unroll
                for (int j = 0; j < CKK; ++j) {
                    if (lv[j] == 1) {
                        float dx = x[i] - x[j], dy = y[i] - y[j], dz = z[i] - z[j];
                        mind = fminf(mind, dx * dx + dy * dy + dz * dz);
                    }
                }
                convexSum += mind;
            }
        }
        acc += convexSum * (1.0f / (BATCH * NCLS));
    }

#pragma unroll
    for (int o = 32; o > 0; o >>= 1) acc += __shfl_down(acc, o, 64);
    __shared__ float s_part[4];
    const int wave = tid >> 6, lane = tid & 63;
    if (lane == 0) s_part[wave] = acc;
    __syncthreads();
    if (tid == 0) {
        atomicAdd(out, s_part[0] + s_part[1] + s_part[2] + s_part[3]);
    }
}

extern "C" void kernel_launch(void* const* d_in, const int* in_sizes, int n_in,
                              void* d_out, int out_size, void* d_ws, size_t ws_size,
                              hipStream_t stream) {
    const float* xyz = (const float*)d_in[0];
    const float* skel = (const float*)d_in[1];
    // d_in[2] = weights (unused by reference)
    const int* labels = (const int*)d_in[3];
    float* out = (float*)d_out;

    float4* skelN = (float4*)d_ws;
    float4* ptsM = (float4*)((float*)d_ws + OFF_PTSM);
    float* tileMins = (float*)d_ws + OFF_TMIN;
    float* partials = (float*)d_ws + OFF_PART;

    k_prep<<<512, 256, 0, stream>>>(xyz, skel, skelN, ptsM, out);
    k_chamfer<<<512, 256, 0, stream>>>(skelN, ptsM, tileMins, partials);
    k_reduce<<<64, 256, 0, stream>>>(skel, labels, tileMins, partials, out);
}

// Round 7
// 93.104 us; speedup vs baseline: 1.1842x; 1.1260x over previous
//
#include <hip/hip_runtime.h>

#define BATCH 8
#define NPTS 16384
#define MSKEL 1000
#define NCLS 100
#define CKK 10
#define MINDIS_INITF 100000.0f

// ws layout (16B aligned):
//   skelN  : float4[8000]   (-sx,-sy,-sz, 0.5|s|^2) per (b,m)
//   ptsM   : float4[131072] (x,y,z, 0.5|p|^2)       per (b,n)
//   minbits: uint[8000]     per-(b,m) min d^2 as uint bits
#define OFF_PTSM 32000
#define OFF_MINB (32000 + 524288)

// prep: build skelN and ptsM; init minbits to +inf; zero output accumulator.
__global__ __launch_bounds__(256) void k_prep(const float* __restrict__ xyz,
                                              const float* __restrict__ skel,
                                              float4* __restrict__ skelN,
                                              float4* __restrict__ ptsM,
                                              unsigned int* __restrict__ minbits,
                                              float* __restrict__ out) {
    const int gid = blockIdx.x * 256 + threadIdx.x;  // 131072 threads exactly
    {
        const float* p = xyz + (size_t)gid * 6;
        float x = p[0], y = p[1], z = p[2];
        ptsM[gid] = make_float4(x, y, z, 0.5f * (x * x + y * y + z * z));
    }
    if (gid < BATCH * MSKEL) {
        const float* s = skel + (size_t)gid * 3;
        float sx = s[0], sy = s[1], sz = s[2];
        skelN[gid] = make_float4(-sx, -sy, -sz, 0.5f * (sx * sx + sy * sy + sz * sz));
        minbits[gid] = 0x7F800000u;  // +inf
    }
    if (gid == 0) out[0] = 0.0f;
}

// Fused chamfer, 512 blocks (2/CU).
//   blocks [0,256):   n-side — 512-pt tile; each LANE owns 8 points (pt =
//                     j*64+lane), each WAVE owns a 250-skel slice → 32 VALU
//                     per uniform s_load (latency fully hidden, 4x fewer
//                     scalar loads). Cross-wave min via LDS, block-sum,
//                     one atomicAdd into out (pre-scaled).
//   blocks [256,512): m-side — 4 skel/thread in regs, 512-pt tile uniform
//                     stream; d^2 = 2*min_t + |s|^2 → atomicMin(minbits).
__global__ __launch_bounds__(256) void k_chamfer(const float4* __restrict__ skelN,
                                                 const float4* __restrict__ ptsM,
                                                 unsigned int* __restrict__ minbits,
                                                 float* __restrict__ out) {
    const int bid = blockIdx.x;
    const int tid = threadIdx.x;

    if (bid < 256) {
        // ---------------- n-side ----------------
        const int b = bid >> 5, tile = bid & 31;
        const int wave = tid >> 6, lane = tid & 63;
        const float4* __restrict__ base = ptsM + b * NPTS + tile * 512;

        float4 P[8];
        float mt[8];
#pragma unroll
        for (int j = 0; j < 8; ++j) {
            P[j] = base[j * 64 + lane];  // coalesced dwordx4
            mt[j] = 3.4e38f;
        }

        const float4* __restrict__ sk = skelN + b * MSKEL + wave * 250;
#pragma unroll 5
        for (int m = 0; m < 250; ++m) {
            float4 s = sk[m];  // uniform -> s_load_dwordx4, 32 VALU inst behind it
#pragma unroll
            for (int j = 0; j < 8; ++j) {
                float t = fmaf(P[j].x, s.x, fmaf(P[j].y, s.y, fmaf(P[j].z, s.z, s.w)));
                mt[j] = fminf(mt[j], t);
            }
        }

        // combine across the 4 wave-slices: sm[wave][pt] = mt + 0.5|p|^2
        __shared__ float sm[4 * 512];
#pragma unroll
        for (int j = 0; j < 8; ++j) {
            sm[wave * 512 + j * 64 + lane] = mt[j] + P[j].w;
        }
        __syncthreads();

        // thread tid finalizes points tid and tid+256
        float a0 = fminf(fminf(sm[tid], sm[512 + tid]),
                         fminf(sm[1024 + tid], sm[1536 + tid]));
        float a1 = fminf(fminf(sm[tid + 256], sm[512 + tid + 256]),
                         fminf(sm[1024 + tid + 256], sm[1536 + tid + 256]));
        float d = sqrtf(fmaxf(2.0f * a0, 1e-12f)) + sqrtf(fmaxf(2.0f * a1, 1e-12f));

#pragma unroll
        for (int o = 32; o > 0; o >>= 1) d += __shfl_down(d, o, 64);
        __shared__ float s_part[4];
        if (lane == 0) s_part[wave] = d;
        __syncthreads();
        if (tid == 0) {
            atomicAdd(out, 0.0125f * (s_part[0] + s_part[1] + s_part[2] + s_part[3]));
        }
    } else {
        // ---------------- m-side ----------------
        const int id = bid - 256;
        const int b = id >> 5, tile = id & 31;

        float nsx[4], nsy[4], nsz[4], ssq[4], mind[4];
#pragma unroll
        for (int k = 0; k < 4; ++k) {
            const int m = tid + k * 256;
            if (m < MSKEL) {
                float4 s = skelN[b * MSKEL + m];  // coalesced
                nsx[k] = s.x; nsy[k] = s.y; nsz[k] = s.z;  // already -s
                ssq[k] = 2.0f * s.w;                        // |s|^2
            } else {
                nsx[k] = 0.0f; nsy[k] = 0.0f; nsz[k] = 0.0f; ssq[k] = 0.0f;
            }
            mind[k] = 3.4e38f;
        }

        const float4* __restrict__ pp = ptsM + b * NPTS + tile * 512;
#pragma unroll 8
        for (int n = 0; n < 512; ++n) {
            float4 r = pp[n];  // uniform -> s_load_dwordx4
#pragma unroll
            for (int k = 0; k < 4; ++k) {
                // t = 0.5|p|^2 - p.s ; d^2 = 2t + |s|^2
                float t = fmaf(r.x, nsx[k], fmaf(r.y, nsy[k], fmaf(r.z, nsz[k], r.w)));
                mind[k] = fminf(mind[k], t);
            }
        }
#pragma unroll
        for (int k = 0; k < 4; ++k) {
            const int m = tid + k * 256;
            if (m < MSKEL) {
                float d2 = fmaf(2.0f, mind[k], ssq[k]);
                // clamp fp-cancellation negatives so uint order == float order
                atomicMin(&minbits[b * MSKEL + m], __float_as_uint(fmaxf(d2, 0.0f)));
            }
        }
    }
}

// reduce: m-side mins (32 KB) + convex-hull term; atomicAdd into out.
__global__ __launch_bounds__(256) void k_reduce(const float* __restrict__ skel,
                                                const int* __restrict__ labels,
                                                const unsigned int* __restrict__ minbits,
                                                float* __restrict__ out) {
    const int gid = blockIdx.x * 256 + threadIdx.x;  // 8 blocks = 2048 threads
    const int tid = threadIdx.x;
    float acc = 0.0f;

    for (int i = gid; i < BATCH * MSKEL; i += 2048) {
        acc += 0.0125f * sqrtf(fmaxf(__uint_as_float(minbits[i]), 1e-12f));
    }

    if (gid < BATCH * NCLS) {
        const int b = gid / NCLS, c = gid - b * NCLS;
        const float* cp = skel + ((size_t)b * MSKEL + c * CKK) * 3;
        const int* lab = labels + (size_t)b * NCLS * CKK + c * CKK;
        float x[CKK], y[CKK], z[CKK];
        int lv[CKK];
#pragma unroll
        for (int i = 0; i < CKK; ++i) {
            x[i] = cp[i * 3 + 0]; y[i] = cp[i * 3 + 1]; z[i] = cp[i * 3 + 2];
            lv[i] = lab[i];
        }
        float convexSum = 0.0f;
#pragma unroll
        for (int i = 0; i < CKK; ++i) {
            if (lv[i] != 1) {
                float mind = MINDIS_INITF;
#pragma unroll
                for (int j = 0; j < CKK; ++j) {
                    if (lv[j] == 1) {
                        float dx = x[i] - x[j], dy = y[i] - y[j], dz = z[i] - z[j];
                        mind = fminf(mind, dx * dx + dy * dy + dz * dz);
                    }
                }
                convexSum += mind;
            }
        }
        acc += convexSum * (1.0f / (BATCH * NCLS));
    }

#pragma unroll
    for (int o = 32; o > 0; o >>= 1) acc += __shfl_down(acc, o, 64);
    __shared__ float s_part[4];
    const int wave = tid >> 6, lane = tid & 63;
    if (lane == 0) s_part[wave] = acc;
    __syncthreads();
    if (tid == 0) {
        atomicAdd(out, s_part[0] + s_part[1] + s_part[2] + s_part[3]);
    }
}

extern "C" void kernel_launch(void* const* d_in, const int* in_sizes, int n_in,
                              void* d_out, int out_size, void* d_ws, size_t ws_size,
                              hipStream_t stream) {
    const float* xyz = (const float*)d_in[0];
    const float* skel = (const float*)d_in[1];
    // d_in[2] = weights (unused by reference)
    const int* labels = (const int*)d_in[3];
    float* out = (float*)d_out;

    float4* skelN = (float4*)d_ws;
    float4* ptsM = (float4*)((float*)d_ws + OFF_PTSM);
    unsigned int* minbits = (unsigned int*)((float*)d_ws + OFF_MINB);

    k_prep<<<512, 256, 0, stream>>>(xyz, skel, skelN, ptsM, minbits, out);
    k_chamfer<<<512, 256, 0, stream>>>(skelN, ptsM, minbits, out);
    k_reduce<<<8, 256, 0, stream>>>(skel, labels, minbits, out);
}